// Round 10
// baseline (166.725 us; speedup 1.0000x reference)
//
#include <hip/hip_runtime.h>
#include <math.h>

#define EPS 1e-6f
#define LN_EPS 1e-5f

static constexpr int Bn = 2, Tn = 2048, Dn = 512, Hn = 8, KT = 2, DH = 64, NC = Tn / 64;
static constexpr int QS = 1536;   // fused qkv bf16 row stride (cols: q|k|v)
static constexpr int NW = 1664;   // padded GEMM width: qkv 1536 | gate 16 | alpha 8 | pad 104

typedef __bf16 bfrag8 __attribute__((ext_vector_type(8)));
typedef float ffrag4 __attribute__((ext_vector_type(4)));
typedef unsigned short us8v __attribute__((ext_vector_type(8)));

__device__ __forceinline__ float wred_sum(float v) {
#pragma unroll
  for (int o = 32; o > 0; o >>= 1) v += __shfl_xor(v, o, 64);
  return v;
}
__device__ __forceinline__ float wred_max(float v) {
#pragma unroll
  for (int o = 32; o > 0; o >>= 1) v = fmaxf(v, __shfl_xor(v, o, 64));
  return v;
}
__device__ __forceinline__ float sigmoidf_(float v) { return 1.0f / (1.0f + expf(-v)); }
__device__ __forceinline__ unsigned short f2bf(float f) {
  unsigned u = __builtin_bit_cast(unsigned, f);
  return (unsigned short)((u + 0x7FFFu + ((u >> 16) & 1u)) >> 16);
}
__device__ __forceinline__ float bf2f(unsigned short u) {
  unsigned v = ((unsigned)u) << 16;
  return __builtin_bit_cast(float, v);
}

// ---------------------------------------------------------------------------
// fp32 -> bf16, WEIGHTS ONLY: [Wq;Wk;Wv;Wg;Wa;pad] -> Wc (1664x512); Wo->Wob.
// grid covers 278528 float4 slots exactly (1088 blocks).
// ---------------------------------------------------------------------------
__global__ __launch_bounds__(256) void conv_bf16(const float* __restrict__ Wq,
                                                 const float* __restrict__ Wk,
                                                 const float* __restrict__ Wv,
                                                 const float* __restrict__ Wo,
                                                 const float* __restrict__ Wg,
                                                 const float* __restrict__ Wa,
                                                 unsigned short* __restrict__ Wc,
                                                 unsigned short* __restrict__ Wob) {
  int idx = blockIdx.x * 256 + threadIdx.x;  // float4 index
  if (idx < 265216) {
    const float* src;
    unsigned short* dst;
    int off;
    if (idx < 65536)       { src = Wq; dst = Wc;           off = idx; }
    else if (idx < 131072) { src = Wk; dst = Wc + 262144;  off = idx - 65536; }
    else if (idx < 196608) { src = Wv; dst = Wc + 524288;  off = idx - 131072; }
    else if (idx < 262144) { src = Wo; dst = Wob;          off = idx - 196608; }
    else if (idx < 264192) { src = Wg; dst = Wc + 786432;  off = idx - 262144; }
    else                   { src = Wa; dst = Wc + 794624;  off = idx - 264192; }
    float4 v = *(const float4*)&src[(size_t)off * 4];
    ushort4 o;
    o.x = f2bf(v.x); o.y = f2bf(v.y); o.z = f2bf(v.z); o.w = f2bf(v.w);
    *(ushort4*)&dst[(size_t)off * 4] = o;
  } else {
    int off = idx - 265216;  // zero pad rows 1560..1663
    ushort4 z = {0, 0, 0, 0};
    *(ushort4*)&Wc[798720 + (size_t)off * 4] = z;
  }
}

// ---------------------------------------------------------------------------
// QKV GEMM: 512 threads, 128x128 tile, BK=32, depth-2 register prefetch.
// A is fp32 x, converted to bf16 at LDS-staging time (identical bf16 values
// to the old conv path). Epilogue: bf16 qkv / sigmoid gate / alpha.
// ---------------------------------------------------------------------------
__global__ __launch_bounds__(512) void gemm_qkv(const float* __restrict__ X,
                                                const unsigned short* __restrict__ W,
                                                const float* __restrict__ bg,
                                                const float* __restrict__ ba,
                                                unsigned short* __restrict__ qkvb,
                                                float* __restrict__ gate,
                                                float* __restrict__ alpha) {
  __shared__ unsigned short As[4096];
  __shared__ unsigned short Bs[4096];
  const int tid = threadIdx.x;
  const int lane = tid & 63, wave = tid >> 6;
  const int m0 = blockIdx.y * 128, n0 = blockIdx.x * 128;
  const int mw = (wave >> 1) * 2, nw = (wave & 1) * 4;

  ffrag4 acc[2][4];
#pragma unroll
  for (int i = 0; i < 2; ++i)
#pragma unroll
    for (int j = 0; j < 4; ++j) acc[i][j] = (ffrag4){0.f, 0.f, 0.f, 0.f};

  const float* ag =
      X + (size_t)(m0 + (tid >> 6) * 16 + (tid & 15)) * Dn + ((tid >> 4) & 3) * 8;
  const unsigned short* wg =
      W + (size_t)(n0 + (tid >> 6) * 16 + (tid & 15)) * Dn + ((tid >> 4) & 3) * 8;
  float4 pa0a = *(const float4*)ag, pa0b = *(const float4*)(ag + 4);
  uint4 pb0 = *(const uint4*)wg;
  float4 pa1a = *(const float4*)(ag + 32), pa1b = *(const float4*)(ag + 36);
  uint4 pb1 = *(const uint4*)(wg + 32);

  for (int k0 = 0; k0 < Dn; k0 += 32) {
    __syncthreads();
    {
      float a8[8] = {pa0a.x, pa0a.y, pa0a.z, pa0a.w, pa0b.x, pa0b.y, pa0b.z, pa0b.w};
      us8v av;
#pragma unroll
      for (int j = 0; j < 8; ++j) av[j] = f2bf(a8[j]);
      *(us8v*)&As[tid * 8] = av;
      *(uint4*)&Bs[tid * 8] = pb0;
    }
    __syncthreads();
    pa0a = pa1a; pa0b = pa1b; pb0 = pb1;
    if (k0 + 64 < Dn) {
      pa1a = *(const float4*)(ag + k0 + 64);
      pa1b = *(const float4*)(ag + k0 + 68);
      pb1 = *(const uint4*)(wg + k0 + 64);
    }
    bfrag8 af[2], bf_[4];
#pragma unroll
    for (int mt = 0; mt < 2; ++mt)
      af[mt] = __builtin_bit_cast(bfrag8, *(const uint4*)&As[((mw + mt) * 64 + lane) * 8]);
#pragma unroll
    for (int nt = 0; nt < 4; ++nt)
      bf_[nt] = __builtin_bit_cast(bfrag8, *(const uint4*)&Bs[((nw + nt) * 64 + lane) * 8]);
#pragma unroll
    for (int mt = 0; mt < 2; ++mt)
#pragma unroll
      for (int nt = 0; nt < 4; ++nt)
        acc[mt][nt] = __builtin_amdgcn_mfma_f32_16x16x32_bf16(af[mt], bf_[nt], acc[mt][nt], 0, 0, 0);
  }

  const int quad = lane >> 4, l15 = lane & 15;
#pragma unroll
  for (int nt = 0; nt < 4; ++nt) {
    int col = n0 + (nw + nt) * 16 + l15;
#pragma unroll
    for (int mt = 0; mt < 2; ++mt) {
#pragma unroll
      for (int r = 0; r < 4; ++r) {
        int row = m0 + (mw + mt) * 16 + quad * 4 + r;
        float val = acc[mt][nt][r];
        if (col < 1536) {
          qkvb[(size_t)row * QS + col] = f2bf(val);
        } else if (col < 1552) {
          gate[(size_t)row * (Hn * KT) + (col - 1536)] = sigmoidf_(val + bg[col - 1536]);
        } else if (col < 1560) {
          alpha[(size_t)row * Hn + (col - 1552)] = sigmoidf_(val + ba[col - 1552]);
        }
      }
    }
  }
}

// ---------------------------------------------------------------------------
// Out-proj GEMM: 256 threads, 64x64 tile, BK=32, depth-2 register prefetch.
// ---------------------------------------------------------------------------
__global__ __launch_bounds__(256) void gemm_out(const unsigned short* __restrict__ A,
                                                const unsigned short* __restrict__ W,
                                                const float* __restrict__ bias,
                                                float* __restrict__ C) {
  __shared__ unsigned short As[2048];
  __shared__ unsigned short Bs[2048];
  const int tid = threadIdx.x;
  const int lane = tid & 63, wave = tid >> 6;
  const int m0 = blockIdx.y * 64, n0 = blockIdx.x * 64;
  const int mw = (wave >> 1) * 2, nw = (wave & 1) * 2;

  ffrag4 acc[2][2];
#pragma unroll
  for (int i = 0; i < 2; ++i)
#pragma unroll
    for (int j = 0; j < 2; ++j) acc[i][j] = (ffrag4){0.f, 0.f, 0.f, 0.f};

  const unsigned short* ag =
      A + (size_t)(m0 + (tid >> 6) * 16 + (tid & 15)) * Dn + ((tid >> 4) & 3) * 8;
  const unsigned short* wg =
      W + (size_t)(n0 + (tid >> 6) * 16 + (tid & 15)) * Dn + ((tid >> 4) & 3) * 8;
  uint4 pa0 = *(const uint4*)ag;
  uint4 pb0 = *(const uint4*)wg;
  uint4 pa1 = *(const uint4*)(ag + 32);
  uint4 pb1 = *(const uint4*)(wg + 32);

  for (int k0 = 0; k0 < Dn; k0 += 32) {
    __syncthreads();
    *(uint4*)&As[tid * 8] = pa0;
    *(uint4*)&Bs[tid * 8] = pb0;
    __syncthreads();
    pa0 = pa1; pb0 = pb1;
    if (k0 + 64 < Dn) {
      pa1 = *(const uint4*)(ag + k0 + 64);
      pb1 = *(const uint4*)(wg + k0 + 64);
    }
    bfrag8 af[2], bf_[2];
#pragma unroll
    for (int mt = 0; mt < 2; ++mt)
      af[mt] = __builtin_bit_cast(bfrag8, *(const uint4*)&As[((mw + mt) * 64 + lane) * 8]);
#pragma unroll
    for (int nt = 0; nt < 2; ++nt)
      bf_[nt] = __builtin_bit_cast(bfrag8, *(const uint4*)&Bs[((nw + nt) * 64 + lane) * 8]);
#pragma unroll
    for (int mt = 0; mt < 2; ++mt)
#pragma unroll
      for (int nt = 0; nt < 2; ++nt)
        acc[mt][nt] = __builtin_amdgcn_mfma_f32_16x16x32_bf16(af[mt], bf_[nt], acc[mt][nt], 0, 0, 0);
  }

  const int quad = lane >> 4, l15 = lane & 15;
#pragma unroll
  for (int nt = 0; nt < 2; ++nt) {
    int col = n0 + (nw + nt) * 16 + l15;
    float bb = bias[col];
#pragma unroll
    for (int mt = 0; mt < 2; ++mt) {
#pragma unroll
      for (int r = 0; r < 4; ++r) {
        int row = m0 + (mw + mt) * 16 + quad * 4 + r;
        C[(size_t)row * Dn + col] = acc[mt][nt][r] + bb;
      }
    }
  }
}

// ---------------------------------------------------------------------------
// Block per (b,h,c): S_k = K^T @ (w_k o V) via MFMA (fp32 S out), z_k via wred,
// sval exported for attn. K/V staged TRANSPOSED ([d][t], stride 72) so all
// fragment gathers are single ds_read_b128.
// ---------------------------------------------------------------------------
__global__ __launch_bounds__(256) void chunk_sums(const unsigned short* __restrict__ qkvb,
                                                  const float* __restrict__ gate,
                                                  const float* __restrict__ decay,
                                                  float* __restrict__ S,
                                                  float* __restrict__ Zc,
                                                  float* __restrict__ svalb) {
  __shared__ unsigned short sKt[64 * 72];  // K^T: addr d*72 + t
  __shared__ unsigned short sVt[64 * 72];  // V^T
  __shared__ float red8[64][8];            // per-t |k| partials by d-group
  __shared__ float sval_s[64];
  __shared__ float gk[KT][64];
  __shared__ float pwr[KT][64];
  __shared__ float wcomb[KT][64];
  const int c = blockIdx.x, h = blockIdx.y, b = blockIdx.z;
  const int c0 = c * 64;
  const int tid = threadIdx.x, wave = tid >> 6, lane = tid & 63;
  const int quad = lane >> 4, l15 = lane & 15;

  {
    int rt = tid >> 3, t0 = rt * 2, dg = tid & 7, d0 = dg * 8;
    const size_t r0 = (size_t)(b * Tn + c0 + t0) * QS + h * DH + d0;
    const size_t r1 = (size_t)(b * Tn + c0 + t0 + 1) * QS + h * DH + d0;
    us8v k0 = *(const us8v*)&qkvb[r0 + 512];
    us8v k1 = *(const us8v*)&qkvb[r1 + 512];
    us8v v0 = *(const us8v*)&qkvb[r0 + 1024];
    us8v v1 = *(const us8v*)&qkvb[r1 + 1024];
    float s0 = 0.f, s1 = 0.f;
#pragma unroll
    for (int j = 0; j < 8; ++j) {
      ushort2 pk; pk.x = k0[j]; pk.y = k1[j];
      *(ushort2*)&sKt[(d0 + j) * 72 + t0] = pk;
      ushort2 pv; pv.x = v0[j]; pv.y = v1[j];
      *(ushort2*)&sVt[(d0 + j) * 72 + t0] = pv;
      s0 += fabsf(bf2f(k0[j]));
      s1 += fabsf(bf2f(k1[j]));
    }
    red8[t0][dg] = s0;
    red8[t0 + 1][dg] = s1;
  }
  if (tid < 128) {
    int s = tid >> 1, k2 = tid & 1;
    gk[k2][s] = gate[((size_t)(b * Tn + c0 + s) * Hn + h) * KT + k2];
  } else {
    int t2 = tid - 128;
    int k2 = t2 >> 6, d = t2 & 63;
    pwr[k2][d] = powf(sigmoidf_(decay[h * KT + k2]), (float)d);
  }
  __syncthreads();
  if (tid < 64) {
    float sv = (red8[tid][0] + red8[tid][1] + red8[tid][2] + red8[tid][3] +
                red8[tid][4] + red8[tid][5] + red8[tid][6] + red8[tid][7]) *
                   (1.f / 64.f) + EPS;
    sval_s[tid] = sv;
    svalb[((size_t)(b * Hn + h)) * Tn + c0 + tid] = sv;
  }
  if (tid >= 128) {
    int t2 = tid - 128;
    int k2 = t2 >> 6, d = t2 & 63;
    wcomb[k2][d] = gk[k2][d] * pwr[k2][63 - d];
  }
  __syncthreads();
  if (wave < 2) {
    const int kx = wave;
    float v = wcomb[kx][lane] * sval_s[lane];
    v = wred_sum(v);
    if (lane == 0) Zc[((size_t)((b * Hn + h) * KT + kx)) * NC + c] = v;
  }

  // A-operand: K^T[m][t] — one b128 per fragment
  const int m_glob = wave * 16 + l15;
  us8v kf[2];
#pragma unroll
  for (int ks = 0; ks < 2; ++ks)
    kf[ks] = *(const us8v*)&sKt[m_glob * 72 + ks * 32 + quad * 8];

#pragma unroll
  for (int k = 0; k < KT; ++k) {
    us8v bv[4][2];
#pragma unroll
    for (int nt = 0; nt < 4; ++nt)
#pragma unroll
      for (int ks = 0; ks < 2; ++ks) {
        int n = nt * 16 + l15;
        int tb = ks * 32 + quad * 8;
        us8v vv = *(const us8v*)&sVt[n * 72 + tb];
        float4 w0 = *(const float4*)&wcomb[k][tb];
        float4 w1 = *(const float4*)&wcomb[k][tb + 4];
        float w8[8] = {w0.x, w0.y, w0.z, w0.w, w1.x, w1.y, w1.z, w1.w};
#pragma unroll
        for (int j = 0; j < 8; ++j) bv[nt][ks][j] = f2bf(w8[j] * bf2f(vv[j]));
      }
    ffrag4 acc[4];
#pragma unroll
    for (int nt = 0; nt < 4; ++nt) acc[nt] = (ffrag4){0.f, 0.f, 0.f, 0.f};
#pragma unroll
    for (int nt = 0; nt < 4; ++nt)
#pragma unroll
      for (int ks = 0; ks < 2; ++ks)
        acc[nt] = __builtin_amdgcn_mfma_f32_16x16x32_bf16(
            __builtin_bit_cast(bfrag8, kf[ks]), __builtin_bit_cast(bfrag8, bv[nt][ks]), acc[nt], 0, 0, 0);
    const size_t sb = ((size_t)((b * Hn + h) * KT + k) * NC + c) * 4096;
#pragma unroll
    for (int nt = 0; nt < 4; ++nt)
#pragma unroll
      for (int r = 0; r < 4; ++r)
        S[sb + (size_t)(wave * 16 + quad * 4 + r) * 64 + nt * 16 + l15] = acc[nt][r];
  }
}

// ---------------------------------------------------------------------------
// Serial scan: fp32 S in, fp32 accumulator, bf16 Hinit out. Batch-4 loads.
// ---------------------------------------------------------------------------
__global__ __launch_bounds__(256) void scan_chunks(const float* __restrict__ S,
                                                   const float* __restrict__ Zc,
                                                   const float* __restrict__ decay,
                                                   unsigned short* __restrict__ Hinit,
                                                   float* __restrict__ Zinit) {
  const int bhk = blockIdx.x, slice = blockIdx.y;
  const int k = bhk % KT, h = (bhk / KT) % Hn;
  const float lam = sigmoidf_(decay[h * KT + k]);
  const float lam64 = powf(lam, 64.f);
  const int tid = threadIdx.x;
  const size_t base = (size_t)bhk * NC * 4096 + (size_t)slice * 512 + (size_t)tid * 2;
  float2 st = {0.f, 0.f};
  float2 sv[4];
#pragma unroll
  for (int j = 0; j < 4; ++j) sv[j] = *(const float2*)&S[base + (size_t)j * 4096];
  for (int cb = 0; cb < NC; cb += 4) {
    float2 nx[4] = {sv[0], sv[1], sv[2], sv[3]};
    if (cb + 4 < NC) {
#pragma unroll
      for (int j = 0; j < 4; ++j) nx[j] = *(const float2*)&S[base + (size_t)(cb + 4 + j) * 4096];
    }
#pragma unroll
    for (int j = 0; j < 4; ++j) {
      size_t off = base + (size_t)(cb + j) * 4096;
      ushort2 o;
      o.x = f2bf(st.x); o.y = f2bf(st.y);
      *(ushort2*)&Hinit[off] = o;
      st.x = lam64 * st.x + sv[j].x;
      st.y = lam64 * st.y + sv[j].y;
    }
#pragma unroll
    for (int j = 0; j < 4; ++j) sv[j] = nx[j];
  }
  if (slice == 0 && tid < 64) {
    float v = (tid < NC) ? Zc[bhk * NC + tid] : 0.f;
    float lp = lam64;
#pragma unroll
    for (int o = 1; o < 32; o <<= 1) {
      float t2 = __shfl_up(v, o, 64);
      if (tid >= o) v += lp * t2;
      lp *= lp;
    }
    float prev = __shfl_up(v, 1, 64);
    if (tid < NC) Zinit[bhk * NC + tid] = (tid == 0) ? 0.f : prev;
  }
}

// ---------------------------------------------------------------------------
// Block per (b,h,c): chunked attention, MFMA everywhere. Hinit/Vc staged
// TRANSPOSED ([d][t], stride 72): fragment gathers = single ds_read_b128.
// ---------------------------------------------------------------------------
__global__ __launch_bounds__(256) void attn_chunk(const unsigned short* __restrict__ qkvb,
                                                  const float* __restrict__ gate,
                                                  const float* __restrict__ alpha,
                                                  const float* __restrict__ decay,
                                                  const unsigned short* __restrict__ Hinit,
                                                  const float* __restrict__ Zinit,
                                                  const float* __restrict__ svalb,
                                                  unsigned short* __restrict__ ypre) {
  __shared__ float sS[64][132];               // raw scores -> probs (33.8 KB)
  __shared__ unsigned short sT16[3 * 4608];   // 3 transposed staging regions
  __shared__ float sval_s[64];
  __shared__ float gk[KT][64];
  __shared__ float sz[KT][64];
  __shared__ float pw[KT][66];
  __shared__ float wt2[KT][64];               // g_s * lam^-s
  __shared__ float zin[KT];

  const int c = blockIdx.x, h = blockIdx.y, b = blockIdx.z;
  const int c0 = c * 64;
  const int tid = threadIdx.x;
  const int wave = tid >> 6, lane = tid & 63;
  const int quad = lane >> 4, l15 = lane & 15;
  const int mt = wave;
  const int rt = tid >> 3, t0 = rt * 2, dg = tid & 7, d0 = dg * 8;

  // ---------------- prologue ----------------
  if (tid < 64) sval_s[tid] = svalb[((size_t)(b * Hn + h)) * Tn + c0 + tid];
  if (tid < 128) {
    int s = tid >> 1, k2 = tid & 1;
    gk[k2][s] = gate[((size_t)(b * Tn + c0 + s) * Hn + h) * KT + k2];
  }
  if (tid >= 128) {
    int t2 = tid - 128;
    int k2 = t2 >> 6, d = t2 & 63;
    float lamv = sigmoidf_(decay[h * KT + k2]);
    pw[k2][d] = powf(lamv, (float)d);
  }
  if (tid < 2) {
    float lamv = sigmoidf_(decay[h * KT + tid]);
    pw[tid][64] = powf(lamv, 64.f);
    zin[tid] = Zinit[((size_t)((b * Hn + h) * KT + tid)) * NC + c];
  }
  __syncthreads();
  if (tid >= 128) {
    int t2 = tid - 128;
    int k2 = t2 >> 6, d = t2 & 63;
    float lamv = sigmoidf_(decay[h * KT + k2]);
    wt2[k2][d] = gk[k2][d] * powf(lamv, -(float)d);
  }
  if (wave < 2) {
    const int kx = wave;
    float v = gk[kx][lane] * sval_s[lane];
#pragma unroll
    for (int o = 1; o < 64; o <<= 1) {
      float t2 = __shfl_up(v, o, 64);
      if (lane >= o) v += pw[kx][o] * t2;
    }
    sz[kx][lane] = v + pw[kx][lane + 1] * zin[kx];
  }
  // wt2/sz consumed in C2, after the staging barrier below.

  // -------- issue staging loads early (regs): Hinit k0,k1 + Vc ------------
  us8v hA[KT], hB[KT], vA, vB;
  {
#pragma unroll
    for (int k = 0; k < KT; ++k) {
      const size_t hb = ((size_t)((b * Hn + h) * KT + k) * NC + c) * 4096;
      hA[k] = *(const us8v*)&Hinit[hb + (size_t)t0 * 64 + d0];
      hB[k] = *(const us8v*)&Hinit[hb + (size_t)(t0 + 1) * 64 + d0];
    }
    vA = *(const us8v*)&qkvb[(size_t)(b * Tn + c0 + t0) * QS + 1024 + h * DH + d0];
    vB = *(const us8v*)&qkvb[(size_t)(b * Tn + c0 + t0 + 1) * QS + 1024 + h * DH + d0];
  }

  // ---------------- Q fragments ----------------
  us8v qf[2];
  {
    const size_t qrow = (size_t)(b * Tn + c0 + mt * 16 + l15) * QS + h * DH;
    qf[0] = *(const us8v*)&qkvb[qrow + quad * 8];
    qf[1] = *(const us8v*)&qkvb[qrow + 32 + quad * 8];
  }

  // ---------------- phase A: raw scores = Qc @ Kwin^T ----------------------
#pragma unroll
  for (int nt = 0; nt < 8; ++nt) {
    int rowg = c0 - 64 + nt * 16 + l15;
    us8v kf0 = (us8v){0, 0, 0, 0, 0, 0, 0, 0}, kf1 = kf0;
    if (rowg >= 0) {
      const size_t kb_ = (size_t)(b * Tn + rowg) * QS + 512 + h * DH;
      kf0 = *(const us8v*)&qkvb[kb_ + quad * 8];
      kf1 = *(const us8v*)&qkvb[kb_ + 32 + quad * 8];
    }
    ffrag4 a = (ffrag4){0.f, 0.f, 0.f, 0.f};
    a = __builtin_amdgcn_mfma_f32_16x16x32_bf16(__builtin_bit_cast(bfrag8, qf[0]),
                                                __builtin_bit_cast(bfrag8, kf0), a, 0, 0, 0);
    a = __builtin_amdgcn_mfma_f32_16x16x32_bf16(__builtin_bit_cast(bfrag8, qf[1]),
                                                __builtin_bit_cast(bfrag8, kf1), a, 0, 0, 0);
#pragma unroll
    for (int r = 0; r < 4; ++r) sS[mt * 16 + quad * 4 + r][nt * 16 + l15] = a[r];
  }

  // -------- commit transposed staging to LDS, single barrier ---------------
#pragma unroll
  for (int j = 0; j < 8; ++j) {
    int da = (d0 + j) * 72 + t0;
    ushort2 p0; p0.x = hA[0][j]; p0.y = hB[0][j];
    *(ushort2*)&sT16[da] = p0;
    ushort2 p1; p1.x = hA[1][j]; p1.y = hB[1][j];
    *(ushort2*)&sT16[4608 + da] = p1;
    ushort2 p2; p2.x = vA[j]; p2.y = vB[j];
    *(ushort2*)&sT16[2 * 4608 + da] = p2;
  }
  __syncthreads();

  // ---------------- phase C1: accH_k = Q @ Hinit_k -------------------------
  ffrag4 accH[KT][4];
#pragma unroll
  for (int k = 0; k < KT; ++k)
#pragma unroll
    for (int nt = 0; nt < 4; ++nt) accH[k][nt] = (ffrag4){0.f, 0.f, 0.f, 0.f};
#pragma unroll
  for (int k = 0; k < KT; ++k) {
#pragma unroll
    for (int nt = 0; nt < 4; ++nt) {
#pragma unroll
      for (int ks = 0; ks < 2; ++ks) {
        us8v g = *(const us8v*)&sT16[k * 4608 + (nt * 16 + l15) * 72 + ks * 32 + quad * 8];
        accH[k][nt] = __builtin_amdgcn_mfma_f32_16x16x32_bf16(
            __builtin_bit_cast(bfrag8, qf[ks]), __builtin_bit_cast(bfrag8, g), accH[k][nt], 0, 0, 0);
      }
    }
  }

  // ---------------- gather Vc B-frags from region 2 ------------------------
  us8v vf[4][2];
#pragma unroll
  for (int nt = 0; nt < 4; ++nt)
#pragma unroll
    for (int ks = 0; ks < 2; ++ks)
      vf[nt][ks] = *(const us8v*)&sT16[2 * 4608 + (nt * 16 + l15) * 72 + ks * 32 + quad * 8];

  // ---------------- phase C2 + combine into accY ---------------------------
  const int i_loc = mt * 16 + l15;
  ffrag4 accY[4];
#pragma unroll
  for (int nt = 0; nt < 4; ++nt) accY[nt] = (ffrag4){0.f, 0.f, 0.f, 0.f};
#pragma unroll
  for (int k = 0; k < KT; ++k) {
    const float lam_i = pw[k][i_loc];
    us8v af[2];
#pragma unroll
    for (int ks = 0; ks < 2; ++ks) {
      int sb_ = ks * 32 + quad * 8;
      float4 p0 = *(const float4*)&sS[i_loc][64 + sb_];
      float4 p1 = *(const float4*)&sS[i_loc][64 + sb_ + 4];
      float4 w0 = *(const float4*)&wt2[k][sb_];
      float4 w1 = *(const float4*)&wt2[k][sb_ + 4];
      float e[8] = {p0.x * w0.x, p0.y * w0.y, p0.z * w0.z, p0.w * w0.w,
                    p1.x * w1.x, p1.y * w1.y, p1.z * w1.z, p1.w * w1.w};
#pragma unroll
      for (int j = 0; j < 8; ++j) {
        float v = (sb_ + j <= i_loc) ? e[j] * lam_i : 0.f;
        af[ks][j] = f2bf(v);
      }
    }
    ffrag4 aD[4];
#pragma unroll
    for (int nt = 0; nt < 4; ++nt) aD[nt] = (ffrag4){0.f, 0.f, 0.f, 0.f};
#pragma unroll
    for (int nt = 0; nt < 4; ++nt)
#pragma unroll
      for (int ks = 0; ks < 2; ++ks)
        aD[nt] = __builtin_amdgcn_mfma_f32_16x16x32_bf16(
            __builtin_bit_cast(bfrag8, af[ks]), __builtin_bit_cast(bfrag8, vf[nt][ks]), aD[nt], 0, 0, 0);
#pragma unroll
    for (int nt = 0; nt < 4; ++nt) {
#pragma unroll
      for (int r = 0; r < 4; ++r) {
        int il = mt * 16 + quad * 4 + r;
        float invz = 1.f / (sz[k][il] + EPS);
        accY[nt][r] += (pw[k][il + 1] * accH[k][nt][r] + aD[nt][r]) * invz;
      }
    }
  }

  // ---------------- phase D: in-place masked ALiBi softmax -----------------
  {
    const float slope = exp2f(-8.f * (float)(h + 1) / (float)Hn);
    for (int rr = 0; rr < 16; ++rr) {
      const int i = mt * 16 + rr;
      float s0v = sS[i][lane], s1v = sS[i][lane + 64];
      bool va = (lane >= i + 1) && (c0 - 64 + lane >= 0);
      bool vb2 = (lane <= i);
      s0v = va  ? s0v - slope * (float)(i + 64 - lane) : -1e30f;
      s1v = vb2 ? s1v - slope * (float)(i - lane) : -1e30f;
      float m = wred_max(fmaxf(s0v, s1v));
      float p0 = __expf(s0v - m), p1 = __expf(s1v - m);
      float inv = 1.f / wred_sum(p0 + p1);
      sS[i][lane] = p0 * inv;
      sS[i][lane + 64] = p1 * inv;
    }
  }

  // ---------------- phase E: yloc = P @ Vwin (cur half reuses vf) ----------
  ffrag4 accL[4];
#pragma unroll
  for (int nt = 0; nt < 4; ++nt) accL[nt] = (ffrag4){0.f, 0.f, 0.f, 0.f};
  us8v pf[2];
#pragma unroll
  for (int ks = 0; ks < 2; ++ks) {
    int sb_ = ks * 32 + quad * 8;
    float4 p0 = *(const float4*)&sS[i_loc][64 + sb_];
    float4 p1 = *(const float4*)&sS[i_loc][64 + sb_ + 4];
    float e[8] = {p0.x, p0.y, p0.z, p0.w, p1.x, p1.y, p1.z, p1.w};
#pragma unroll
    for (int j = 0; j < 8; ++j) pf[ks][j] = f2bf(e[j]);
  }
#pragma unroll
  for (int nt = 0; nt < 4; ++nt)
#pragma unroll
    for (int ks = 0; ks < 2; ++ks)
      accL[nt] = __builtin_amdgcn_mfma_f32_16x16x32_bf16(
          __builtin_bit_cast(bfrag8, pf[ks]), __builtin_bit_cast(bfrag8, vf[nt][ks]), accL[nt], 0, 0, 0);

  // prev-half V -> region 0 (transposed)
  __syncthreads();
  {
    int rowg0 = c0 - 64 + t0;
    us8v z8 = (us8v){0, 0, 0, 0, 0, 0, 0, 0};
    us8v v0 = z8, v1 = z8;
    if (rowg0 >= 0)
      v0 = *(const us8v*)&qkvb[(size_t)(b * Tn + rowg0) * QS + 1024 + h * DH + d0];
    if (rowg0 + 1 >= 0)
      v1 = *(const us8v*)&qkvb[(size_t)(b * Tn + rowg0 + 1) * QS + 1024 + h * DH + d0];
#pragma unroll
    for (int j = 0; j < 8; ++j) {
      ushort2 p; p.x = v0[j]; p.y = v1[j];
      *(ushort2*)&sT16[(d0 + j) * 72 + t0] = p;
    }
  }
  __syncthreads();
#pragma unroll
  for (int ks = 0; ks < 2; ++ks) {
    int sb_ = ks * 32 + quad * 8;
    float4 p0 = *(const float4*)&sS[i_loc][sb_];
    float4 p1 = *(const float4*)&sS[i_loc][sb_ + 4];
    float e[8] = {p0.x, p0.y, p0.z, p0.w, p1.x, p1.y, p1.z, p1.w};
#pragma unroll
    for (int j = 0; j < 8; ++j) pf[ks][j] = f2bf(e[j]);
  }
#pragma unroll
  for (int nt = 0; nt < 4; ++nt) {
#pragma unroll
    for (int ks = 0; ks < 2; ++ks) {
      us8v g = *(const us8v*)&sT16[(nt * 16 + l15) * 72 + ks * 32 + quad * 8];
      accL[nt] = __builtin_amdgcn_mfma_f32_16x16x32_bf16(
          __builtin_bit_cast(bfrag8, pf[ks]), __builtin_bit_cast(bfrag8, g), accL[nt], 0, 0, 0);
    }
  }

  // ---------------- phase F: combine + bf16 write --------------------------
#pragma unroll
  for (int nt = 0; nt < 4; ++nt) {
#pragma unroll
    for (int r = 0; r < 4; ++r) {
      int il = mt * 16 + quad * 4 + r;
      int tt = c0 + il;
      float av = alpha[((size_t)(b * Tn + tt)) * Hn + h];
      float val = av * accL[nt][r] + (1.f - av) * accY[nt][r];
      ypre[(size_t)(b * Tn + tt) * Dn + h * DH + nt * 16 + l15] = f2bf(val);
    }
  }
}

// ---------------------------------------------------------------------------
// out = LayerNorm(x + proj) * gamma + beta
// ---------------------------------------------------------------------------
__global__ __launch_bounds__(256) void ln_kernel(const float* __restrict__ x,
                                                 const float* __restrict__ proj,
                                                 const float* __restrict__ gamma,
                                                 const float* __restrict__ beta,
                                                 float* __restrict__ out) {
  const int row = blockIdx.x;
  const int tid = threadIdx.x;
  const int wave = tid >> 6, lane = tid & 63;
  const size_t base = (size_t)row * Dn;
  __shared__ float red[8];
  float r0 = x[base + tid] + proj[base + tid];
  float r1 = x[base + tid + 256] + proj[base + tid + 256];
  float s = wred_sum(r0 + r1);
  if (lane == 0) red[wave] = s;
  __syncthreads();
  float mu = (red[0] + red[1] + red[2] + red[3]) * (1.f / (float)Dn);
  float d0 = r0 - mu, d1 = r1 - mu;
  float q = wred_sum(d0 * d0 + d1 * d1);
  if (lane == 0) red[4 + wave] = q;
  __syncthreads();
  float var = (red[4] + red[5] + red[6] + red[7]) * (1.f / (float)Dn);
  float inv = rsqrtf(var + LN_EPS);
  out[base + tid]       = d0 * inv * gamma[tid]       + beta[tid];
  out[base + tid + 256] = d1 * inv * gamma[tid + 256] + beta[tid + 256];
}

// ---------------------------------------------------------------------------
extern "C" void kernel_launch(void* const* d_in, const int* in_sizes, int n_in,
                              void* d_out, int out_size, void* d_ws, size_t ws_size,
                              hipStream_t stream) {
  const float* x     = (const float*)d_in[0];
  const float* Wq    = (const float*)d_in[1];
  const float* Wk    = (const float*)d_in[2];
  const float* Wv    = (const float*)d_in[3];
  const float* Wg    = (const float*)d_in[4];
  const float* bg    = (const float*)d_in[5];
  const float* Wa    = (const float*)d_in[6];
  const float* ba    = (const float*)d_in[7];
  const float* Wo    = (const float*)d_in[8];
  const float* bo    = (const float*)d_in[9];
  const float* decay = (const float*)d_in[10];
  const float* gamma = (const float*)d_in[11];
  const float* beta  = (const float*)d_in[12];
  float* out = (float*)d_out;

  const size_t NTOK = (size_t)Bn * Tn;                  // 4096
  const size_t NST  = (size_t)Bn * Hn * KT * NC * 4096; // 4194304 state elems
  float* ws = (float*)d_ws;
  float* proj  = ws; ws += NTOK * Dn;
  float* Sb    = ws; ws += NST;    // fp32 S
  float* gateb = ws; ws += NTOK * Hn * KT;
  float* alphb = ws; ws += NTOK * Hn;
  float* Zcb   = ws; ws += (size_t)Bn * Hn * KT * NC;
  float* Zib   = ws; ws += (size_t)Bn * Hn * KT * NC;
  float* svalb = ws; ws += (size_t)Bn * Hn * Tn;
  unsigned short* us = (unsigned short*)ws;
  unsigned short* Hib  = us; us += NST;                  // bf16 Hinit
  unsigned short* Wc   = us; us += (size_t)NW * Dn;      // 1664x512
  unsigned short* Wob  = us; us += (size_t)Dn * Dn;
  unsigned short* ypre = us; us += NTOK * Dn;
  unsigned short* qkvb = us; us += NTOK * QS;

  conv_bf16<<<1088, 256, 0, stream>>>(Wq, Wk, Wv, Wo, Wg, Wa, Wc, Wob);

  gemm_qkv<<<dim3(NW / 128, (int)NTOK / 128), 512, 0, stream>>>(
      x, Wc, bg, ba, qkvb, gateb, alphb);

  chunk_sums<<<dim3(NC, Hn, Bn), 256, 0, stream>>>(qkvb, gateb, decay, Sb, Zcb, svalb);
  scan_chunks<<<dim3(Bn * Hn * KT, 8), 256, 0, stream>>>(Sb, Zcb, decay, Hib, Zib);

  attn_chunk<<<dim3(NC, Hn, Bn), 256, 0, stream>>>(qkvb, gateb, alphb, decay,
                                                   Hib, Zib, svalb, ypre);

  gemm_out<<<dim3(Dn / 64, (int)NTOK / 64), 256, 0, stream>>>(ypre, Wob, bo, proj);
  ln_kernel<<<(int)NTOK, 256, 0, stream>>>(x, proj, gamma, beta, out);
}